// Round 3
// baseline (1350.713 us; speedup 1.0000x reference)
//
#include <hip/hip_runtime.h>

#define H  64
#define G4 256   // 4*H

typedef float vf4 __attribute__((ext_vector_type(4)));

// fast sigmoid/tanh: v_exp_f32 + v_rcp_f32. Safe at +-inf:
//   x->-inf: exp(-x)=inf -> rcp(inf)=0 ; x->+inf: exp(-x)=0 -> rcp(1)=1
__device__ __forceinline__ float sigm(float x) {
    return __builtin_amdgcn_rcpf(1.0f + __expf(-x));
}
__device__ __forceinline__ float tanh_s(float x) {
    return fmaf(2.0f, sigm(2.0f * x), -1.0f);
}

__device__ __forceinline__ float bcast(float v, int lane) {
    return __int_as_float(__builtin_amdgcn_readlane(__float_as_int(v), lane));
}

// P2[v][e][g] = sum_h table[v][h] * w_ih[g*64+e][h] + b_ih + b_hh, table[0]=0.
// Layout [V][64][4] so the lstm consumer reads its 4 gate inputs as 1 dwordx4.
__global__ __launch_bounds__(256)
void proj_kernel(const float* __restrict__ emb,
                 const float* __restrict__ w_ih,
                 const float* __restrict__ b_ih,
                 const float* __restrict__ b_hh,
                 float* __restrict__ P,
                 int V)
{
    const int j  = threadIdx.x;       // gate row 0..255 (g = j>>6, e = j&63)
    const int v0 = blockIdx.x * 8;

    __shared__ float es[8][H];
    {
        int idx = j;
        #pragma unroll
        for (int rep = 0; rep < 2; ++rep, idx += 256) {
            int r = idx >> 6, col = idx & 63;
            int v = v0 + r;
            float val = 0.0f;
            if (v < V && v != 0) val = emb[v * H + col];   // padding_idx=0
            es[r][col] = val;
        }
    }

    vf4 w[16];
    const vf4* w4 = reinterpret_cast<const vf4*>(w_ih + j * H);
    #pragma unroll
    for (int i = 0; i < 16; ++i) w[i] = w4[i];

    float bias = b_ih[j] + b_hh[j];
    __syncthreads();

    const int slot = (j & 63) * 4 + (j >> 6);   // [e][g] position within row
    #pragma unroll
    for (int r = 0; r < 8; ++r) {
        int v = v0 + r;
        if (v >= V) break;
        float a0 = 0, a1 = 0, a2 = 0, a3 = 0;
        #pragma unroll
        for (int i = 0; i < 16; ++i) {
            a0 = fmaf(es[r][4*i+0], w[i][0], a0);
            a1 = fmaf(es[r][4*i+1], w[i][1], a1);
            a2 = fmaf(es[r][4*i+2], w[i][2], a2);
            a3 = fmaf(es[r][4*i+3], w[i][3], a3);
        }
        P[v * G4 + slot] = bias + ((a0 + a1) + (a2 + a3));
    }
}

// One block (512 threads, 8 waves) per batch element. Split-K structure:
// wave w = (row-group rg=w>>2, k-quarter kq=w&3). Lane owns rows
// {128rg+lane, 128rg+64+lane} restricted to k in [16kq,16kq+16): 32 weights
// (8 VGPRs). 16 readlane broadcasts are shared across 2 rows. Partials are
// exchanged through LDS pl[row][kq] (XOR-swizzled slot -> conflict-free
// writes; reads are contiguous ds_read_b128, order-free sum undoes the
// swizzle). One barrier/step, double-buffered. 2 waves/SIMD hide the
// LDS/barrier/trans latencies that were fully exposed at 1 wave/SIMD.
__global__ __launch_bounds__(512, 2)
void lstm_kernel(const int* __restrict__ x,        // [B,T]
                 const float* __restrict__ P2,     // [V][64][4]
                 const float* __restrict__ w_hh,   // [4H,H] (forward)
                 const float* __restrict__ w_ih_b, // [4H,H]
                 const float* __restrict__ b_ih_b, // [4H]
                 const float* __restrict__ b_hh_b, // [4H]
                 const float* __restrict__ emb,    // [V,H]
                 const float* __restrict__ w_fc,   // [12,2H]
                 const float* __restrict__ b_fc,   // [12]
                 float* __restrict__ out,          // [B,12]
                 int T)
{
    const int b    = blockIdx.x;
    const int tid  = threadIdx.x;
    const int lane = tid & 63;
    const int wv   = tid >> 6;      // 0..7
    const int kq   = wv & 3;        // k in [16kq, 16kq+16)
    const int rg   = wv >> 2;       // rows 128rg + {lane, 64+lane}

    const int r0 = rg * 128 + lane;
    const int r1 = r0 + 64;

    // 32 resident weights: 2 rows x 16 k = 8 vf4
    vf4 w0[4], w1[4];
    {
        const vf4* a = reinterpret_cast<const vf4*>(w_hh + r0 * H + kq * 16);
        const vf4* c4 = reinterpret_cast<const vf4*>(w_hh + r1 * H + kq * 16);
        #pragma unroll
        for (int i = 0; i < 4; ++i) { w0[i] = a[i]; w1[i] = c4[i]; }
    }

    __shared__ float pl[2][256][4];   // [phase][row][kq-slot]
    __shared__ float hf_s[H];
    __shared__ float hb_s[H];
    __shared__ float e_s[H];

    const int* __restrict__ xrow = x + (long)b * T;
    const float* __restrict__ Pme = P2 + lane * 4;   // + tok*G4 -> 16B aligned

    float h = 0.0f;   // lane's h value (replicated across all 8 waves)
    float c = 0.0f;

    int tok_next = (T > 1) ? xrow[1] : 0;
    vf4 p_cur = *reinterpret_cast<const vf4*>(Pme + (size_t)xrow[0] * G4);

    // swizzled partial slot: bank-conflict-free writes (2 lanes/bank)
    const int s = kq ^ ((lane >> 4) & 3);
    float* wr0 = &pl[0][r0][s];
    float* wr1 = &pl[0][r1][s];
    const int kb = kq * 16;

    for (int t = 0; t < T; ++t) {
        // prefetch next timestep's 4 gate inputs (one dwordx4)
        vf4 p_next = *reinterpret_cast<const vf4*>(Pme + (size_t)tok_next * G4);
        int tok_next2 = (t + 2 < T) ? xrow[t + 2] : 0;

        // partial dot: 16 broadcasts shared across 2 rows
        float a00 = 0, a01 = 0, a10 = 0, a11 = 0;
        #pragma unroll
        for (int m = 0; m < 16; m += 2) {
            float hb0 = bcast(h, kb + m);
            float hb1 = bcast(h, kb + m + 1);
            a00 = fmaf(w0[m >> 2][m & 3], hb0, a00);
            a10 = fmaf(w1[m >> 2][m & 3], hb0, a10);
            a01 = fmaf(w0[(m + 1) >> 2][(m + 1) & 3], hb1, a01);
            a11 = fmaf(w1[(m + 1) >> 2][(m + 1) & 3], hb1, a11);
        }
        float part0 = a00 + a01;
        float part1 = a10 + a11;

        const int ph = t & 1;
        wr0[ph * 1024] = part0;
        wr1[ph * 1024] = part1;
        // lgkmcnt-only barrier: LDS writes visible, global prefetch (vmcnt)
        // stays in flight across the barrier.
        asm volatile("s_waitcnt lgkmcnt(0)" ::: "memory");
        __builtin_amdgcn_s_barrier();

        // consumer (replicated in every wave): element `lane`
        const vf4* pb = reinterpret_cast<const vf4*>(pl[ph]);
        vf4 qi = pb[lane];
        vf4 qf = pb[64 + lane];
        vf4 qg = pb[128 + lane];
        vf4 qo = pb[192 + lane];
        float si = ((qi[0] + qi[1]) + (qi[2] + qi[3])) + p_cur[0];
        float sf = ((qf[0] + qf[1]) + (qf[2] + qf[3])) + p_cur[1];
        float sg = ((qg[0] + qg[1]) + (qg[2] + qg[3])) + p_cur[2];
        float so = ((qo[0] + qo[1]) + (qo[2] + qo[3])) + p_cur[3];

        float i_ = sigm(si);
        float f_ = sigm(sf);
        float g_ = tanh_s(sg);
        float o_ = sigm(so);
        c = fmaf(f_, c, i_ * g_);
        h = o_ * tanh_s(c);

        p_cur    = p_next;
        tok_next = tok_next2;
    }

    // ---- epilogue ----
    // backward LSTM = exactly one step (hs_b[0]) with zero initial state:
    // gates = w_ih_b . emb[last_token] + biases, computed directly.
    int tokL = xrow[T - 1];
    if (wv == 0) hf_s[lane] = h;
    if (tid < H) e_s[tid] = (tokL != 0) ? emb[tokL * H + tid] : 0.0f;
    __syncthreads();

    float* gb_s = reinterpret_cast<float*>(pl);   // reuse partial buffer
    if (tid < 256) {
        float accb = 0.0f;
        const vf4* wb4 = reinterpret_cast<const vf4*>(w_ih_b + tid * H);
        #pragma unroll
        for (int i = 0; i < 16; ++i) {
            vf4 wq = wb4[i];
            accb = fmaf(wq[0], e_s[4*i+0], accb);
            accb = fmaf(wq[1], e_s[4*i+1], accb);
            accb = fmaf(wq[2], e_s[4*i+2], accb);
            accb = fmaf(wq[3], e_s[4*i+3], accb);
        }
        float gb = accb + b_ih_b[tid] + b_hh_b[tid];
        gb_s[tid] = ((tid >> 6) == 2) ? tanh_s(gb) : sigm(gb);
    }
    __syncthreads();

    if (tid < H) {
        float i_ = gb_s[tid];
        float gg = gb_s[2*H + tid];
        float go = gb_s[3*H + tid];
        float cb = i_ * gg;               // f*c0 = 0
        hb_s[tid] = go * tanh_s(cb);
    }
    __syncthreads();

    // final FC: y[b, j] = b_fc[j] + [h_f | h_b] . w_fc[j]
    if (tid < 12) {
        float acc = b_fc[tid];
        const float* wf = w_fc + tid * (2 * H);
        #pragma unroll
        for (int k = 0; k < H; ++k) acc = fmaf(hf_s[k], wf[k], acc);
        #pragma unroll
        for (int k = 0; k < H; ++k) acc = fmaf(hb_s[k], wf[H + k], acc);
        out[b * 12 + tid] = acc;
    }
}

extern "C" void kernel_launch(void* const* d_in, const int* in_sizes, int n_in,
                              void* d_out, int out_size, void* d_ws, size_t ws_size,
                              hipStream_t stream)
{
    const int*   x      = (const int*)  d_in[0];
    const float* emb    = (const float*)d_in[1];
    const float* w_ih_f = (const float*)d_in[2];
    const float* w_hh_f = (const float*)d_in[3];
    const float* b_ih_f = (const float*)d_in[4];
    const float* b_hh_f = (const float*)d_in[5];
    const float* w_ih_b = (const float*)d_in[6];
    // d_in[7] = w_hh_b (unused: backward runs exactly one step from zero state)
    const float* b_ih_b = (const float*)d_in[8];
    const float* b_hh_b = (const float*)d_in[9];
    const float* w_fc   = (const float*)d_in[10];
    const float* b_fc   = (const float*)d_in[11];
    float* out = (float*)d_out;

    const int B = out_size / 12;
    const int T = in_sizes[0] / B;
    const int V = in_sizes[1] / H;

    float* Pf = (float*)d_ws;                   // [V][64][4] (2 MB)

    int pblocks = (V + 7) / 8;
    proj_kernel<<<pblocks, 256, 0, stream>>>(emb, w_ih_f, b_ih_f, b_hh_f, Pf, V);
    lstm_kernel<<<B, 512, 0, stream>>>(x, Pf, w_hh_f, w_ih_b, b_ih_b, b_hh_b,
                                       emb, w_fc, b_fc, out, T);
}